// Round 1
// baseline (1735.747 us; speedup 1.0000x reference)
//
#include <hip/hip_runtime.h>
#include <hip/hip_bf16.h>
#include <math.h>

#define NN 50000
#define NE 800000
#define NR 16
#define DD 64
#define OSTRIDE 192   // 3*D concat output stride

// ---------- helpers ----------
__device__ inline unsigned f2mono(float f) {
    unsigned u = __float_as_uint(f);
    return (u & 0x80000000u) ? ~u : (u | 0x80000000u);
}
__device__ inline float mono2f(unsigned u) {
    return __uint_as_float((u & 0x80000000u) ? (u ^ 0x80000000u) : ~u);
}

// ---------- kernels ----------
// h0 = entity_embed[node_ids] -> out[:, 0:64]
__global__ void k_copy_h0(const int* __restrict__ node_ids,
                          const float* __restrict__ ent,
                          float* __restrict__ out, int n_nodes) {
    int i = blockIdx.x * blockDim.x + threadIdx.x;
    if (i >= n_nodes * DD) return;
    int n = i >> 6, d = i & 63;
    out[(size_t)n * OSTRIDE + d] = ent[(size_t)node_ids[n] * DD + d];
}

// trans[n, r, :] = h[n, :] @ W[r]    (W: [16][64][64] row-major, trans[e]=sum_d h[d]*W[d][e])
// block: 256 threads, 16 nodes per block. thread t: node = t>>4, cols = (t&15)*4 .. +3
__global__ void k_trans(const float* __restrict__ out, int off_in,
                        const float* __restrict__ W,
                        float* __restrict__ trans) {
    __shared__ float hs[16][65];
    int n0 = blockIdx.x * 16;
    int t = threadIdx.x;
    for (int i = t; i < 16 * 64; i += 256) {
        int ni = i >> 6, d = i & 63;
        hs[ni][d] = out[(size_t)(n0 + ni) * OSTRIDE + off_in + d];
    }
    __syncthreads();
    int ni = t >> 4;
    int e4 = (t & 15) * 4;
    const float* hrow = hs[ni];
    for (int r = 0; r < NR; ++r) {
        const float* Wr = W + r * 4096 + e4;
        float4 acc = {0.f, 0.f, 0.f, 0.f};
        #pragma unroll 8
        for (int d = 0; d < 64; ++d) {
            float4 w = *(const float4*)(Wr + d * 64);
            float hv = hrow[d];
            acc.x += hv * w.x; acc.y += hv * w.y;
            acc.z += hv * w.z; acc.w += hv * w.w;
        }
        *(float4*)&trans[(((size_t)(n0 + ni)) * NR + r) * DD + e4] = acc;
    }
}

// att[e] = sum_d trans[src,et,d] * tanh(trans[dst,et,d] + relE[et,d]); one wave per edge
__global__ void k_att_trans(const float* __restrict__ trans,
                            const float* __restrict__ relE,
                            const int* __restrict__ src, const int* __restrict__ dst,
                            const int* __restrict__ et,
                            float* __restrict__ att) {
    int e = blockIdx.x * 4 + (threadIdx.x >> 6);
    if (e >= NE) return;
    int lane = threadIdx.x & 63;
    int r = et[e], s = src[e], dn = dst[e];
    float ts = trans[(((size_t)s) * NR + r) * DD + lane];
    float td = trans[(((size_t)dn) * NR + r) * DD + lane];
    float ef = relE[r * DD + lane];
    float v = ts * tanhf(td + ef);
    #pragma unroll
    for (int o = 32; o; o >>= 1) v += __shfl_xor(v, o, 64);
    if (lane == 0) att[e] = v;
}

// fallback (no trans workspace): per-edge matvecs via shfl broadcast of h rows
__global__ void k_att_direct(const float* __restrict__ out, int off_in,
                             const float* __restrict__ W,
                             const float* __restrict__ relE,
                             const int* __restrict__ src, const int* __restrict__ dst,
                             const int* __restrict__ et,
                             float* __restrict__ att) {
    int e = blockIdx.x * 4 + (threadIdx.x >> 6);
    if (e >= NE) return;
    int lane = threadIdx.x & 63;
    int r = et[e], s = src[e], dn = dst[e];
    float hsv = out[(size_t)s * OSTRIDE + off_in + lane];
    float hdv = out[(size_t)dn * OSTRIDE + off_in + lane];
    const float* Wr = W + r * 4096;
    float ts = 0.f, td = 0.f;
    for (int k = 0; k < 64; ++k) {
        float w = Wr[k * 64 + lane];
        ts += w * __shfl(hsv, k, 64);
        td += w * __shfl(hdv, k, 64);
    }
    float ef = relE[r * DD + lane];
    float v = ts * tanhf(td + ef);
    #pragma unroll
    for (int o = 32; o; o >>= 1) v += __shfl_xor(v, o, 64);
    if (lane == 0) att[e] = v;
}

__global__ void k_segmax(const float* __restrict__ att, const int* __restrict__ dst,
                         unsigned* __restrict__ m) {
    for (int e = blockIdx.x * blockDim.x + threadIdx.x; e < NE;
         e += gridDim.x * blockDim.x)
        atomicMax(&m[dst[e]], f2mono(att[e]));
}

__global__ void k_exp(float* __restrict__ att, const int* __restrict__ dst,
                      const unsigned* __restrict__ m, float* __restrict__ z) {
    for (int e = blockIdx.x * blockDim.x + threadIdx.x; e < NE;
         e += gridDim.x * blockDim.x) {
        int dn = dst[e];
        float v = __expf(att[e] - mono2f(m[dn]));
        att[e] = v;
        atomicAdd(&z[dn], v);
    }
}

// h_nb[dst] += (att/z[dst]) * h[src]; one wave per edge
__global__ void k_scatter(const float* __restrict__ att, const float* __restrict__ z,
                          const float* __restrict__ out, int off_in,
                          const int* __restrict__ src, const int* __restrict__ dst,
                          float* __restrict__ h_nb) {
    int e = blockIdx.x * 4 + (threadIdx.x >> 6);
    if (e >= NE) return;
    int lane = threadIdx.x & 63;
    int s = src[e], dn = dst[e];
    float a = att[e] / z[dn];
    atomicAdd(&h_nb[dn * DD + lane], a * out[(size_t)s * OSTRIDE + off_in + lane]);
}

// out[:, off_out] = leaky((h+h_nb)@ra) + leaky((h*h_nb)@rb); one wave per node
__global__ void k_out(const float* __restrict__ h_nb,
                      const float* __restrict__ ra, const float* __restrict__ rb,
                      float* __restrict__ out, int off_in, int off_out) {
    int n = blockIdx.x * 4 + (threadIdx.x >> 6);
    if (n >= NN) return;
    int lane = threadIdx.x & 63;
    float h  = out[(size_t)n * OSTRIDE + off_in + lane];
    float nb = h_nb[n * DD + lane];
    float v1 = h + nb, v2 = h * nb;
    float a1 = 0.f, a2 = 0.f;
    for (int k = 0; k < 64; ++k) {
        float b1 = __shfl(v1, k, 64);
        float b2 = __shfl(v2, k, 64);
        a1 += b1 * ra[k * 64 + lane];
        a2 += b2 * rb[k * 64 + lane];
    }
    a1 = a1 > 0.f ? a1 : 0.01f * a1;
    a2 = a2 > 0.f ? a2 : 0.01f * a2;
    out[(size_t)n * OSTRIDE + off_out + lane] = a1 + a2;
}

// ---------- launch ----------
extern "C" void kernel_launch(void* const* d_in, const int* in_sizes, int n_in,
                              void* d_out, int out_size, void* d_ws, size_t ws_size,
                              hipStream_t stream) {
    const int*   node_ids = (const int*)d_in[0];
    const int*   rel_ids  = (const int*)d_in[1];
    const int*   src      = (const int*)d_in[2];
    const int*   dst      = (const int*)d_in[3];
    const float* ent      = (const float*)d_in[4];
    const float* relE     = (const float*)d_in[5];
    const float* W[2]  = {(const float*)d_in[6], (const float*)d_in[7]};
    const float* ra[2] = {(const float*)d_in[8], (const float*)d_in[10]};
    const float* rb[2] = {(const float*)d_in[9], (const float*)d_in[11]};
    float* out = (float*)d_out;

    // workspace carve
    const size_t trans_bytes = (size_t)NN * NR * DD * sizeof(float);   // 204.8 MB
    const size_t hnb_bytes   = (size_t)NN * DD * sizeof(float);        // 12.8 MB
    const size_t att_bytes   = (size_t)NE * sizeof(float);             // 3.2 MB
    const size_t mz_bytes    = (size_t)NN * sizeof(float);             // 0.2 MB each
    const size_t planA_total = trans_bytes + hnb_bytes + att_bytes + 2 * mz_bytes;
    bool planA = ws_size >= planA_total;

    char* p = (char*)d_ws;
    float* trans = nullptr;
    if (planA) { trans = (float*)p; p += trans_bytes; }
    float*    h_nb = (float*)p; p += hnb_bytes;
    float*    att  = (float*)p; p += att_bytes;
    unsigned* mbuf = (unsigned*)p; p += mz_bytes;
    float*    z    = (float*)p;

    // h0
    k_copy_h0<<<(NN * DD + 255) / 256, 256, 0, stream>>>(node_ids, ent, out, NN);

    for (int L = 0; L < 2; ++L) {
        int off_in = L * DD;        // 0 or 64
        int off_out = (L + 1) * DD; // 64 or 128

        hipMemsetAsync(h_nb, 0, hnb_bytes, stream);
        hipMemsetAsync(mbuf, 0, 2 * mz_bytes, stream); // m (mono-uint 0 == -inf) and z

        if (planA) {
            k_trans<<<NN / 16, 256, 0, stream>>>(out, off_in, W[L], trans);
            k_att_trans<<<NE / 4, 256, 0, stream>>>(trans, relE, src, dst, rel_ids, att);
        } else {
            k_att_direct<<<NE / 4, 256, 0, stream>>>(out, off_in, W[L], relE,
                                                     src, dst, rel_ids, att);
        }
        k_segmax<<<1024, 256, 0, stream>>>(att, dst, mbuf);
        k_exp<<<1024, 256, 0, stream>>>(att, dst, mbuf, z);
        k_scatter<<<NE / 4, 256, 0, stream>>>(att, z, out, off_in, src, dst, h_nb);
        k_out<<<NN / 4 + 1, 256, 0, stream>>>(h_nb, ra[L], rb[L], out, off_in, off_out);
    }
}

// Round 2
// 1225.140 us; speedup vs baseline: 1.4168x; 1.4168x over previous
//
#include <hip/hip_runtime.h>
#include <hip/hip_bf16.h>
#include <math.h>

#define NN 50000
#define NE 800000
#define NR 16
#define DD 64
#define OSTRIDE 192   // 3*D concat output stride

// ---------- helpers ----------
__device__ inline unsigned f2mono(float f) {
    unsigned u = __float_as_uint(f);
    return (u & 0x80000000u) ? ~u : (u | 0x80000000u);
}
__device__ inline float mono2f(unsigned u) {
    return __uint_as_float((u & 0x80000000u) ? (u ^ 0x80000000u) : ~u);
}

// ---------- kernels ----------
// h0 = entity_embed[node_ids] -> out[:, 0:64]
__global__ void k_copy_h0(const int* __restrict__ node_ids,
                          const float* __restrict__ ent,
                          float* __restrict__ out, int n_nodes) {
    int i = blockIdx.x * blockDim.x + threadIdx.x;
    if (i >= n_nodes * DD) return;
    int n = i >> 6, d = i & 63;
    out[(size_t)n * OSTRIDE + d] = ent[(size_t)node_ids[n] * DD + d];
}

// trans[n, r, :] = h[n, :] @ W[r]
// LDS-tiled GEMM: 64 nodes/block, 2 relations per pass, thread = 4 nodes x 2 rel x 4 cols.
__global__ __launch_bounds__(256) void k_trans2(const float* __restrict__ outbuf, int off_in,
                                                const float* __restrict__ W,
                                                float* __restrict__ trans) {
    __shared__ float hs[64][68];        // [k][node], pad 68 -> aligned, conflict-free
    __shared__ float ws[2][64][64];     // [rl][k][col]
    int t = threadIdx.x;
    int n0 = blockIdx.x * 64;

    // stage h transposed: hs[k][ni] = out[(n0+ni)*192 + off_in + k]
    for (int i = t; i < 1024; i += 256) {         // 1024 float4 chunks
        int ni = i >> 4, c4 = (i & 15) * 4;
        int n = n0 + ni;
        float4 v = make_float4(0.f, 0.f, 0.f, 0.f);
        if (n < NN) v = *(const float4*)&outbuf[(size_t)n * OSTRIDE + off_in + c4];
        hs[c4 + 0][ni] = v.x;
        hs[c4 + 1][ni] = v.y;
        hs[c4 + 2][ni] = v.z;
        hs[c4 + 3][ni] = v.w;
    }

    int nd0 = (t >> 4) * 4;      // 4 nodes
    int c0  = (t & 15) * 4;      // 4 cols (same cols in both staged relations)

    for (int rr = 0; rr < 8; ++rr) {
        __syncthreads();          // protect ws from previous pass readers
        const float* Wbase = W + rr * 2 * 4096;
        for (int i = t; i < 2048; i += 256) {     // 2 relations * 1024 float4
            float4 v = *(const float4*)&Wbase[i * 4];
            int rl = i >> 10, rem = i & 1023;
            int k = rem >> 4, c4 = (rem & 15) * 4;
            *(float4*)&ws[rl][k][c4] = v;
        }
        __syncthreads();

        float acc[4][2][4] = {};
        #pragma unroll 8
        for (int k = 0; k < 64; ++k) {
            float4 h4 = *(const float4*)&hs[k][nd0];
            float4 wa = *(const float4*)&ws[0][k][c0];
            float4 wb = *(const float4*)&ws[1][k][c0];
            float hh[4] = {h4.x, h4.y, h4.z, h4.w};
            #pragma unroll
            for (int i = 0; i < 4; ++i) {
                acc[i][0][0] += hh[i] * wa.x; acc[i][0][1] += hh[i] * wa.y;
                acc[i][0][2] += hh[i] * wa.z; acc[i][0][3] += hh[i] * wa.w;
                acc[i][1][0] += hh[i] * wb.x; acc[i][1][1] += hh[i] * wb.y;
                acc[i][1][2] += hh[i] * wb.z; acc[i][1][3] += hh[i] * wb.w;
            }
        }

        #pragma unroll
        for (int i = 0; i < 4; ++i) {
            int n = n0 + nd0 + i;
            if (n < NN) {
                #pragma unroll
                for (int rl = 0; rl < 2; ++rl) {
                    int r = rr * 2 + rl;
                    *(float4*)&trans[(((size_t)n) * NR + r) * DD + c0] =
                        make_float4(acc[i][rl][0], acc[i][rl][1],
                                    acc[i][rl][2], acc[i][rl][3]);
                }
            }
        }
    }
}

// att[e] = sum_d trans[src,et,d] * tanh(trans[dst,et,d] + relE[et,d]); one wave per edge
__global__ void k_att_trans(const float* __restrict__ trans,
                            const float* __restrict__ relE,
                            const int* __restrict__ src, const int* __restrict__ dst,
                            const int* __restrict__ et,
                            float* __restrict__ att) {
    int e = blockIdx.x * 4 + (threadIdx.x >> 6);
    if (e >= NE) return;
    int lane = threadIdx.x & 63;
    int r = et[e], s = src[e], dn = dst[e];
    float ts = trans[(((size_t)s) * NR + r) * DD + lane];
    float td = trans[(((size_t)dn) * NR + r) * DD + lane];
    float ef = relE[r * DD + lane];
    float v = ts * tanhf(td + ef);
    #pragma unroll
    for (int o = 32; o; o >>= 1) v += __shfl_xor(v, o, 64);
    if (lane == 0) att[e] = v;
}

__global__ void k_segmax(const float* __restrict__ att, const int* __restrict__ dst,
                         unsigned* __restrict__ m) {
    for (int e = blockIdx.x * blockDim.x + threadIdx.x; e < NE;
         e += gridDim.x * blockDim.x)
        atomicMax(&m[dst[e]], f2mono(att[e]));
}

__global__ void k_exp(float* __restrict__ att, const int* __restrict__ dst,
                      const unsigned* __restrict__ m, float* __restrict__ z) {
    for (int e = blockIdx.x * blockDim.x + threadIdx.x; e < NE;
         e += gridDim.x * blockDim.x) {
        int dn = dst[e];
        float v = __expf(att[e] - mono2f(m[dn]));
        att[e] = v;
        atomicAdd(&z[dn], v);
    }
}

// h_nb[dst] += (att/z[dst]) * h[src]; one wave per edge
__global__ void k_scatter(const float* __restrict__ att, const float* __restrict__ z,
                          const float* __restrict__ out, int off_in,
                          const int* __restrict__ src, const int* __restrict__ dst,
                          float* __restrict__ h_nb) {
    int e = blockIdx.x * 4 + (threadIdx.x >> 6);
    if (e >= NE) return;
    int lane = threadIdx.x & 63;
    int s = src[e], dn = dst[e];
    float a = att[e] / z[dn];
    atomicAdd(&h_nb[dn * DD + lane], a * out[(size_t)s * OSTRIDE + off_in + lane]);
}

// out[:, off_out] = leaky((h+h_nb)@ra) + leaky((h*h_nb)@rb); one wave per node
__global__ void k_out(const float* __restrict__ h_nb,
                      const float* __restrict__ ra, const float* __restrict__ rb,
                      float* __restrict__ out, int off_in, int off_out) {
    int n = blockIdx.x * 4 + (threadIdx.x >> 6);
    if (n >= NN) return;
    int lane = threadIdx.x & 63;
    float h  = out[(size_t)n * OSTRIDE + off_in + lane];
    float nb = h_nb[n * DD + lane];
    float v1 = h + nb, v2 = h * nb;
    float a1 = 0.f, a2 = 0.f;
    for (int k = 0; k < 64; ++k) {
        float b1 = __shfl(v1, k, 64);
        float b2 = __shfl(v2, k, 64);
        a1 += b1 * ra[k * 64 + lane];
        a2 += b2 * rb[k * 64 + lane];
    }
    a1 = a1 > 0.f ? a1 : 0.01f * a1;
    a2 = a2 > 0.f ? a2 : 0.01f * a2;
    out[(size_t)n * OSTRIDE + off_out + lane] = a1 + a2;
}

// ---------- launch ----------
extern "C" void kernel_launch(void* const* d_in, const int* in_sizes, int n_in,
                              void* d_out, int out_size, void* d_ws, size_t ws_size,
                              hipStream_t stream) {
    const int*   node_ids = (const int*)d_in[0];
    const int*   rel_ids  = (const int*)d_in[1];
    const int*   src      = (const int*)d_in[2];
    const int*   dst      = (const int*)d_in[3];
    const float* ent      = (const float*)d_in[4];
    const float* relE     = (const float*)d_in[5];
    const float* W[2]  = {(const float*)d_in[6], (const float*)d_in[7]};
    const float* ra[2] = {(const float*)d_in[8], (const float*)d_in[10]};
    const float* rb[2] = {(const float*)d_in[9], (const float*)d_in[11]};
    float* out = (float*)d_out;

    // workspace carve
    const size_t trans_bytes = (size_t)NN * NR * DD * sizeof(float);   // 204.8 MB
    const size_t hnb_bytes   = (size_t)NN * DD * sizeof(float);        // 12.8 MB
    const size_t att_bytes   = (size_t)NE * sizeof(float);             // 3.2 MB
    const size_t mz_bytes    = (size_t)NN * sizeof(float);             // 0.2 MB each

    char* p = (char*)d_ws;
    float* trans = (float*)p; p += trans_bytes;
    float*    h_nb = (float*)p; p += hnb_bytes;
    float*    att  = (float*)p; p += att_bytes;
    unsigned* mbuf = (unsigned*)p; p += mz_bytes;
    float*    z    = (float*)p;

    // h0
    k_copy_h0<<<(NN * DD + 255) / 256, 256, 0, stream>>>(node_ids, ent, out, NN);

    for (int L = 0; L < 2; ++L) {
        int off_in = L * DD;        // 0 or 64
        int off_out = (L + 1) * DD; // 64 or 128

        hipMemsetAsync(h_nb, 0, hnb_bytes, stream);
        hipMemsetAsync(mbuf, 0, 2 * mz_bytes, stream); // m (mono-uint 0 == -inf) and z

        k_trans2<<<(NN + 63) / 64, 256, 0, stream>>>(out, off_in, W[L], trans);
        k_att_trans<<<NE / 4, 256, 0, stream>>>(trans, relE, src, dst, rel_ids, att);
        k_segmax<<<1024, 256, 0, stream>>>(att, dst, mbuf);
        k_exp<<<1024, 256, 0, stream>>>(att, dst, mbuf, z);
        k_scatter<<<NE / 4, 256, 0, stream>>>(att, z, out, off_in, src, dst, h_nb);
        k_out<<<NN / 4 + 1, 256, 0, stream>>>(h_nb, ra[L], rb[L], out, off_in, off_out);
    }
}

// Round 3
// 780.181 us; speedup vs baseline: 2.2248x; 1.5703x over previous
//
#include <hip/hip_runtime.h>
#include <hip/hip_bf16.h>
#include <math.h>

#define NN 50000
#define NE 800000
#define NR 16
#define DD 64
#define OSTRIDE 192   // 3*D concat output stride

// ---------- CSR build ----------
__global__ void k_deg(const int* __restrict__ dst, int* __restrict__ cnt) {
    for (int e = blockIdx.x * blockDim.x + threadIdx.x; e < NE;
         e += gridDim.x * blockDim.x)
        atomicAdd(&cnt[dst[e]], 1);
}

// single-block exclusive scan over cnt[NN] -> rowptr[NN+1]; resets cnt to rowptr (cursor)
__global__ __launch_bounds__(1024) void k_scan(int* __restrict__ cnt,
                                               int* __restrict__ rowptr) {
    __shared__ int part[1024];
    int t = threadIdx.x;
    const int CH = (NN + 1023) / 1024;   // 49
    int lo = t * CH, hi = lo + CH > NN ? NN : lo + CH;
    int s = 0;
    for (int i = lo; i < hi; ++i) s += cnt[i];
    part[t] = s;
    __syncthreads();
    for (int o = 1; o < 1024; o <<= 1) {
        int v = (t >= o) ? part[t - o] : 0;
        __syncthreads();
        part[t] += v;
        __syncthreads();
    }
    int run = (t == 0) ? 0 : part[t - 1];
    for (int i = lo; i < hi; ++i) {
        int d = cnt[i];
        rowptr[i] = run;
        cnt[i] = run;        // becomes the fill cursor
        run += d;
    }
    if (t == 1023) rowptr[NN] = run;
}

__global__ void k_fill(const int* __restrict__ dst, int* __restrict__ cursor,
                       int* __restrict__ eidx) {
    for (int e = blockIdx.x * blockDim.x + threadIdx.x; e < NE;
         e += gridDim.x * blockDim.x) {
        int pos = atomicAdd(&cursor[dst[e]], 1);
        eidx[pos] = e;
    }
}

// ---------- h0 gather ----------
__global__ void k_copy_h0(const int* __restrict__ node_ids,
                          const float* __restrict__ ent,
                          float* __restrict__ out) {
    int i = blockIdx.x * blockDim.x + threadIdx.x;
    if (i >= NN * DD) return;
    int n = i >> 6, d = i & 63;
    out[(size_t)n * OSTRIDE + d] = ent[(size_t)node_ids[n] * DD + d];
}

// ---------- trans GEMM: trans[n,r,:] = h[n,:] @ W[r] ----------
__global__ __launch_bounds__(256) void k_trans2(const float* __restrict__ outbuf, int off_in,
                                                const float* __restrict__ W,
                                                float* __restrict__ trans) {
    __shared__ float hs[64][68];
    __shared__ float ws[2][64][64];
    int t = threadIdx.x;
    int n0 = blockIdx.x * 64;

    for (int i = t; i < 1024; i += 256) {
        int ni = i >> 4, c4 = (i & 15) * 4;
        int n = n0 + ni;
        float4 v = make_float4(0.f, 0.f, 0.f, 0.f);
        if (n < NN) v = *(const float4*)&outbuf[(size_t)n * OSTRIDE + off_in + c4];
        hs[c4 + 0][ni] = v.x;
        hs[c4 + 1][ni] = v.y;
        hs[c4 + 2][ni] = v.z;
        hs[c4 + 3][ni] = v.w;
    }

    int nd0 = (t >> 4) * 4;
    int c0  = (t & 15) * 4;

    for (int rr = 0; rr < 8; ++rr) {
        __syncthreads();
        const float* Wbase = W + rr * 2 * 4096;
        for (int i = t; i < 2048; i += 256) {
            float4 v = *(const float4*)&Wbase[i * 4];
            int rl = i >> 10, rem = i & 1023;
            int k = rem >> 4, c4 = (rem & 15) * 4;
            *(float4*)&ws[rl][k][c4] = v;
        }
        __syncthreads();

        float acc[4][2][4] = {};
        #pragma unroll 8
        for (int k = 0; k < 64; ++k) {
            float4 h4 = *(const float4*)&hs[k][nd0];
            float4 wa = *(const float4*)&ws[0][k][c0];
            float4 wb = *(const float4*)&ws[1][k][c0];
            float hh[4] = {h4.x, h4.y, h4.z, h4.w};
            #pragma unroll
            for (int i = 0; i < 4; ++i) {
                acc[i][0][0] += hh[i] * wa.x; acc[i][0][1] += hh[i] * wa.y;
                acc[i][0][2] += hh[i] * wa.z; acc[i][0][3] += hh[i] * wa.w;
                acc[i][1][0] += hh[i] * wb.x; acc[i][1][1] += hh[i] * wb.y;
                acc[i][1][2] += hh[i] * wb.z; acc[i][1][3] += hh[i] * wb.w;
            }
        }

        #pragma unroll
        for (int i = 0; i < 4; ++i) {
            int n = n0 + nd0 + i;
            if (n < NN) {
                #pragma unroll
                for (int rl = 0; rl < 2; ++rl) {
                    int r = rr * 2 + rl;
                    *(float4*)&trans[(((size_t)n) * NR + r) * DD + c0] =
                        make_float4(acc[i][rl][0], acc[i][rl][1],
                                    acc[i][rl][2], acc[i][rl][3]);
                }
            }
        }
    }
}

// ---------- fused attention + softmax + aggregate (one wave per dst node) ----------
__global__ __launch_bounds__(256) void k_fused(const float* __restrict__ trans,
                                               const float* __restrict__ outbuf, int off_in,
                                               const float* __restrict__ relE,
                                               const int* __restrict__ src,
                                               const int* __restrict__ rel,
                                               const int* __restrict__ rowptr,
                                               const int* __restrict__ eidx,
                                               float* __restrict__ h_nb) {
    int n = blockIdx.x * 4 + (threadIdx.x >> 6);
    if (n >= NN) return;
    int lane = threadIdx.x & 63;
    int row0 = rowptr[n], row1 = rowptr[n + 1];
    int deg = row1 - row0;

    float m = -__builtin_inff(), z = 0.f, acc = 0.f;

    // prefetch first edge meta
    int s = 0, r = 0;
    if (deg > 0) {
        int e = eidx[row0];
        s = src[e];
        r = rel[e];
    }

    for (int i = 0; i < deg; ++i) {
        float ts  = trans[(((size_t)s) * NR + r) * DD + lane];
        float hsv = outbuf[(size_t)s * OSTRIDE + off_in + lane];
        float td  = trans[(((size_t)n) * NR + r) * DD + lane];
        float ef  = relE[r * DD + lane];
        // prefetch next edge meta while computing
        if (i + 1 < deg) {
            int e2 = eidx[row0 + i + 1];
            s = src[e2];
            r = rel[e2];
        }
        float v = ts * tanhf(td + ef);
        #pragma unroll
        for (int o = 32; o; o >>= 1) v += __shfl_xor(v, o, 64);
        float mn = fmaxf(m, v);
        float sc = __expf(m - mn);   // m=-inf first iter -> 0
        float w  = __expf(v - mn);
        z   = z * sc + w;
        acc = acc * sc + w * hsv;
        m = mn;
    }

    h_nb[(size_t)n * DD + lane] = (deg > 0) ? acc / z : 0.f;
}

// ---------- epilogue GEMM: out[:,off_out] = leaky((h+nb)@ra) + leaky((h*nb)@rb) ----------
__global__ __launch_bounds__(256) void k_out2(const float* __restrict__ h_nb,
                                              const float* __restrict__ ra,
                                              const float* __restrict__ rb,
                                              float* __restrict__ out,
                                              int off_in, int off_out) {
    __shared__ float v1s[64][68];
    __shared__ float v2s[64][68];
    __shared__ float ws[2][64][64];   // ra, rb
    int t = threadIdx.x;
    int n0 = blockIdx.x * 64;

    for (int i = t; i < 1024; i += 256) {
        int ni = i >> 4, c4 = (i & 15) * 4;
        int n = n0 + ni;
        float4 hv = make_float4(0.f, 0.f, 0.f, 0.f);
        float4 nb = make_float4(0.f, 0.f, 0.f, 0.f);
        if (n < NN) {
            hv = *(const float4*)&out[(size_t)n * OSTRIDE + off_in + c4];
            nb = *(const float4*)&h_nb[(size_t)n * DD + c4];
        }
        v1s[c4 + 0][ni] = hv.x + nb.x;  v2s[c4 + 0][ni] = hv.x * nb.x;
        v1s[c4 + 1][ni] = hv.y + nb.y;  v2s[c4 + 1][ni] = hv.y * nb.y;
        v1s[c4 + 2][ni] = hv.z + nb.z;  v2s[c4 + 2][ni] = hv.z * nb.z;
        v1s[c4 + 3][ni] = hv.w + nb.w;  v2s[c4 + 3][ni] = hv.w * nb.w;
    }
    for (int i = t; i < 2048; i += 256) {
        const float* base = (i < 1024) ? ra : rb;
        int rem = i & 1023;
        float4 v = *(const float4*)&base[rem * 4];
        int k = rem >> 4, c4 = (rem & 15) * 4;
        *(float4*)&ws[i >> 10][k][c4] = v;
    }
    __syncthreads();

    int nd0 = (t >> 4) * 4;
    int c0  = (t & 15) * 4;
    float a1[4][4] = {}, a2[4][4] = {};
    #pragma unroll 8
    for (int k = 0; k < 64; ++k) {
        float4 h1 = *(const float4*)&v1s[k][nd0];
        float4 h2 = *(const float4*)&v2s[k][nd0];
        float4 wa = *(const float4*)&ws[0][k][c0];
        float4 wb = *(const float4*)&ws[1][k][c0];
        float x1[4] = {h1.x, h1.y, h1.z, h1.w};
        float x2[4] = {h2.x, h2.y, h2.z, h2.w};
        #pragma unroll
        for (int i = 0; i < 4; ++i) {
            a1[i][0] += x1[i] * wa.x; a1[i][1] += x1[i] * wa.y;
            a1[i][2] += x1[i] * wa.z; a1[i][3] += x1[i] * wa.w;
            a2[i][0] += x2[i] * wb.x; a2[i][1] += x2[i] * wb.y;
            a2[i][2] += x2[i] * wb.z; a2[i][3] += x2[i] * wb.w;
        }
    }
    #pragma unroll
    for (int i = 0; i < 4; ++i) {
        int n = n0 + nd0 + i;
        if (n >= NN) continue;
        float4 o;
        float* po = (float*)&o;
        #pragma unroll
        for (int j = 0; j < 4; ++j) {
            float u1 = a1[i][j], u2 = a2[i][j];
            u1 = u1 > 0.f ? u1 : 0.01f * u1;
            u2 = u2 > 0.f ? u2 : 0.01f * u2;
            po[j] = u1 + u2;
        }
        *(float4*)&out[(size_t)n * OSTRIDE + off_out + c0] = o;
    }
}

// ---------- launch ----------
extern "C" void kernel_launch(void* const* d_in, const int* in_sizes, int n_in,
                              void* d_out, int out_size, void* d_ws, size_t ws_size,
                              hipStream_t stream) {
    const int*   node_ids = (const int*)d_in[0];
    const int*   rel_ids  = (const int*)d_in[1];
    const int*   src      = (const int*)d_in[2];
    const int*   dst      = (const int*)d_in[3];
    const float* ent      = (const float*)d_in[4];
    const float* relE     = (const float*)d_in[5];
    const float* W[2]  = {(const float*)d_in[6], (const float*)d_in[7]};
    const float* ra[2] = {(const float*)d_in[8], (const float*)d_in[10]};
    const float* rb[2] = {(const float*)d_in[9], (const float*)d_in[11]};
    float* out = (float*)d_out;

    // workspace carve
    const size_t trans_bytes  = (size_t)NN * NR * DD * sizeof(float);  // 204.8 MB
    const size_t hnb_bytes    = (size_t)NN * DD * sizeof(float);       // 12.8 MB
    const size_t eidx_bytes   = (size_t)NE * sizeof(int);              // 3.2 MB
    const size_t rowptr_bytes = (size_t)(NN + 1) * sizeof(int);
    const size_t cnt_bytes    = (size_t)NN * sizeof(int);

    char* p = (char*)d_ws;
    float* trans  = (float*)p; p += trans_bytes;
    float* h_nb   = (float*)p; p += hnb_bytes;
    int*   eidx   = (int*)p;   p += eidx_bytes;
    int*   rowptr = (int*)p;   p += rowptr_bytes;
    int*   cnt    = (int*)p;   p += cnt_bytes;
    (void)ws_size;

    // ---- CSR build (shared by both layers) ----
    hipMemsetAsync(cnt, 0, cnt_bytes, stream);
    k_deg <<<1024, 256, 0, stream>>>(dst, cnt);
    k_scan<<<1, 1024, 0, stream>>>(cnt, rowptr);
    k_fill<<<1024, 256, 0, stream>>>(dst, cnt, eidx);

    // ---- h0 ----
    k_copy_h0<<<(NN * DD + 255) / 256, 256, 0, stream>>>(node_ids, ent, out);

    for (int L = 0; L < 2; ++L) {
        int off_in = L * DD;
        int off_out = (L + 1) * DD;

        k_trans2<<<(NN + 63) / 64, 256, 0, stream>>>(out, off_in, W[L], trans);
        k_fused <<<(NN + 3) / 4, 256, 0, stream>>>(trans, out, off_in, relE,
                                                   src, rel_ids, rowptr, eidx, h_nb);
        k_out2  <<<(NN + 63) / 64, 256, 0, stream>>>(h_nb, ra[L], rb[L], out,
                                                     off_in, off_out);
    }
}